// Round 13
// baseline (137.634 us; speedup 1.0000x reference)
//
#include <hip/hip_runtime.h>

typedef _Float16 f16x8 __attribute__((ext_vector_type(8)));
typedef _Float16 f16x4 __attribute__((ext_vector_type(4)));
typedef float f32x4 __attribute__((ext_vector_type(4)));

#define MFMA32(a, b, c) __builtin_amdgcn_mfma_f32_16x16x32_f16(a, b, c, 0, 0, 0)
#define MFMA16(a, b, c) __builtin_amdgcn_mfma_f32_16x16x16f16(a, b, c, 0, 0, 0)

// ---------------------------------------------------------------- converts
__global__ __launch_bounds__(256) void convert_all(
    const float* __restrict__ x,
    const float* __restrict__ w0, const float* __restrict__ w1,
    const float* __restrict__ w2, const float* __restrict__ w3,
    _Float16* __restrict__ xb,
    _Float16* __restrict__ o0, _Float16* __restrict__ o1,
    _Float16* __restrict__ o2, _Float16* __restrict__ o3) {
  int chunk = blockIdx.x * 256 + threadIdx.x;
  const float* in;
  _Float16* out;
  int i;
  if (chunk < 1048576) {
    in = x; out = xb; i = chunk * 4;
  } else {
    int t = chunk - 1048576;
    int z = t >> 18;
    i = (t & 262143) * 4;
    in = (z == 0) ? w0 : (z == 1) ? w1 : (z == 2) ? w2 : w3;
    out = (z == 0) ? o0 : (z == 1) ? o1 : (z == 2) ? o2 : o3;
  }
  float4 v = *(const float4*)(in + i);
  f16x4 h;
  h.x = (_Float16)v.x; h.y = (_Float16)v.y; h.z = (_Float16)v.z; h.w = (_Float16)v.w;
  *(f16x4*)(out + i) = h;
}

// ---------------------------------------------------------------- GEMM core
// 64(M) x 128(N) tile, BK=64, 4 waves each computing 64x32 (acc 4x2).
__device__ __forceinline__ void gld_lds16(_Float16* l, const _Float16* g) {
  __builtin_amdgcn_global_load_lds(
      (const __attribute__((address_space(1))) unsigned int*)g,
      (__attribute__((address_space(3))) unsigned int*)l, 16, 0, 0);
}

__device__ __forceinline__ void stage64(_Float16* lds, const _Float16* g,
                                        int wid, int lane) {
#pragma unroll
  for (int j = 0; j < 2; ++j) {
    int blk = wid * 2 + j;
    int row = blk * 8 + (lane >> 3);
    int col = (lane & 7) * 8;
    gld_lds16(lds + blk * 512, g + (size_t)row * 1024 + col);
  }
}

__device__ __forceinline__ void stage128(_Float16* lds, const _Float16* g,
                                         int wid, int lane) {
#pragma unroll
  for (int j = 0; j < 4; ++j) {
    int blk = wid * 4 + j;
    int row = blk * 8 + (lane >> 3);
    int col = (lane & 7) * 8;
    gld_lds16(lds + blk * 512, g + (size_t)row * 1024 + col);
  }
}

__device__ __forceinline__ void gemm_core64(const _Float16* __restrict__ A,
                                            const _Float16* __restrict__ W,
                                            _Float16* As, _Float16* Bs,
                                            f32x4 acc[4][2], int m0, int n0, int tid) {
  int lane = tid & 63, wid = tid >> 6;
  int lr = lane & 15, lg = lane >> 4;
  int wn = wid * 32;
  for (int k0 = 0; k0 < 1024; k0 += 64) {
    __syncthreads();
    stage64(As, A + (size_t)m0 * 1024 + k0, wid, lane);
    stage128(Bs, W + (size_t)n0 * 1024 + k0, wid, lane);
    __syncthreads();
#pragma unroll
    for (int ks = 0; ks < 2; ++ks) {
      f16x8 af[4], bfv[2];
#pragma unroll
      for (int mf = 0; mf < 4; ++mf)
        af[mf] = *(const f16x8*)(As + (mf * 16 + lr) * 64 + ks * 32 + lg * 8);
#pragma unroll
      for (int nf = 0; nf < 2; ++nf)
        bfv[nf] = *(const f16x8*)(Bs + (wn + nf * 16 + lr) * 64 + ks * 32 + lg * 8);
#pragma unroll
      for (int mf = 0; mf < 4; ++mf)
#pragma unroll
        for (int nf = 0; nf < 2; ++nf)
          acc[mf][nf] = MFMA32(af[mf], bfv[nf], acc[mf][nf]);
    }
  }
}

// --------------------------------------------------- QKV projection GEMM
#define TRP 72  // Tr stride for 128x64 transpose buffer

__global__ __launch_bounds__(256) void proj_gemm(
    const _Float16* __restrict__ xb,
    const _Float16* __restrict__ wq, const _Float16* __restrict__ wk,
    const _Float16* __restrict__ wv,
    const float* __restrict__ bq, const float* __restrict__ bk,
    const float* __restrict__ bv,
    _Float16* __restrict__ qo, _Float16* __restrict__ ko, _Float16* __restrict__ vo) {
  __shared__ __align__(16) _Float16 smem[12288];   // As 4096 + Bs 8192 halves
  _Float16* As = smem;
  _Float16* Bs = smem + 4096;
  int z = blockIdx.z;
  const _Float16* W = (z == 0) ? wq : ((z == 1) ? wk : wv);
  const float* bias = (z == 0) ? bq : ((z == 1) ? bk : bv);
  int tid = threadIdx.x;
  int m0 = blockIdx.x * 64, n0 = blockIdx.y * 128;
  f32x4 acc[4][2] = {};
  gemm_core64(xb, W, As, Bs, acc, m0, n0, tid);

  int lane = tid & 63, wid = tid >> 6;
  int lr = lane & 15, lg = lane >> 4;
  int wn = wid * 32;

  if (z == 2) {
    _Float16* Tr = smem;                 // reuse As/Bs: 128*72 = 9216 <= 12288
    int b = m0 >> 11, s0 = m0 & 2047;
    __syncthreads();
#pragma unroll
    for (int nf = 0; nf < 2; ++nf) {
      int c = wn + nf * 16 + lr;
      float bb = bias[n0 + c];
#pragma unroll
      for (int mf = 0; mf < 4; ++mf)
#pragma unroll
        for (int i = 0; i < 4; ++i)
          Tr[c * TRP + mf * 16 + lg * 4 + i] = (_Float16)(acc[mf][nf][i] + bb);
    }
    __syncthreads();
#pragma unroll
    for (int j = 0; j < 4; ++j) {
      int cid = tid + 256 * j;
      int c = cid >> 3, seg = cid & 7;
      int cg = n0 + c, h = cg >> 6, hd = cg & 63;
      f16x8 v = *(const f16x8*)(Tr + c * TRP + seg * 8);
      *(f16x8*)(vo + ((size_t)(b * 16 + h) * 64 + hd) * 2048 + s0 + seg * 8) = v;
    }
  } else {
    _Float16* o = (z == 0) ? qo : ko;
#pragma unroll
    for (int nf = 0; nf < 2; ++nf) {
      int col = n0 + wn + nf * 16 + lr;
      float bb = bias[col];
      int h = col >> 6, hd = col & 63;
#pragma unroll
      for (int mf = 0; mf < 4; ++mf)
#pragma unroll
        for (int i = 0; i < 4; ++i) {
          int row = m0 + mf * 16 + lg * 4 + i;
          int b = row >> 11, s = row & 2047;
          o[((size_t)(b * 16 + h) * 2048 + s) * 64 + hd] = (_Float16)(acc[mf][nf][i] + bb);
        }
    }
  }
}

// --------------------------------------------------------- output GEMM (f32)
__global__ __launch_bounds__(256) void out_gemm(
    const _Float16* __restrict__ attn, const _Float16* __restrict__ wo,
    const float* __restrict__ bo, float* __restrict__ out) {
  __shared__ __align__(16) _Float16 smem[12288];
  _Float16* As = smem;
  _Float16* Bs = smem + 4096;
  int tid = threadIdx.x;
  int m0 = blockIdx.x * 64, n0 = blockIdx.y * 128;
  f32x4 acc[4][2] = {};
  gemm_core64(attn, wo, As, Bs, acc, m0, n0, tid);

  int lane = tid & 63, wid = tid >> 6;
  int lr = lane & 15, lg = lane >> 4;
  int wn = wid * 32;
#pragma unroll
  for (int nf = 0; nf < 2; ++nf) {
    int col = n0 + wn + nf * 16 + lr;
    float bb = bo[col];
#pragma unroll
    for (int mf = 0; mf < 4; ++mf)
#pragma unroll
      for (int i = 0; i < 4; ++i) {
        int row = m0 + mf * 16 + lg * 4 + i;
        out[(size_t)row * 1024 + col] = acc[mf][nf][i] + bb;
      }
  }
}

// --------------------------------------------------------- flash attention v12
// SPLIT-KV: grid (16,16,4) = 1024 blocks (z = b*2 + half); each block does
// half of its (qt,h,b)'s kv tiles -> 4 blocks/CU, 4 waves/SIMD (was 2).
// Per-tile math + dbuf loop verbatim r12 (passed). Final write: unnormalized
// O~ (f16) + per-row (m,l); a combine kernel merges the two halves.
#define LDP 72  // padded LDS stride (halves)

template <bool MASK>
__device__ __forceinline__ void attn_tile32(const _Float16* Ks, const _Float16* Vs,
                                            const f16x8 qb[2][2], int kv0, int qwb,
                                            int lr, int lg,
                                            float m[2], float l[2], f32x4 ot[2][4]) {
  const float L2E = 1.44269504f;
  const float NINF = -__builtin_inff();
  f16x8 kf0[4], kf1[4];
#pragma unroll
  for (int nf = 0; nf < 4; ++nf) {
    kf0[nf] = *(const f16x8*)(Ks + (nf * 16 + lr) * LDP + lg * 8);
    kf1[nf] = *(const f16x8*)(Ks + (nf * 16 + lr) * LDP + 32 + lg * 8);
  }
  f32x4 sc[2][4];
  __builtin_amdgcn_s_setprio(1);
#pragma unroll
  for (int h = 0; h < 2; ++h)
#pragma unroll
    for (int nf = 0; nf < 4; ++nf) {
      f32x4 z = {0.f, 0.f, 0.f, 0.f};
      z = MFMA32(kf0[nf], qb[h][0], z);
      z = MFMA32(kf1[nf], qb[h][1], z);
      sc[h][nf] = z;
    }
  __builtin_amdgcn_s_setprio(0);
  if (MASK) {
#pragma unroll
    for (int h = 0; h < 2; ++h) {
      int qg = qwb + h * 16 + lr;
#pragma unroll
      for (int nf = 0; nf < 4; ++nf)
#pragma unroll
        for (int i = 0; i < 4; ++i) {
          int kg = kv0 + nf * 16 + lg * 4 + i;
          sc[h][nf][i] = (kg <= qg) ? sc[h][nf][i] : NINF;
        }
    }
  }
  f16x4 pf[2][4];
#pragma unroll
  for (int h = 0; h < 2; ++h) {
    f32x4 mx4 = sc[h][0];
#pragma unroll
    for (int nf = 1; nf < 4; ++nf)
#pragma unroll
      for (int i = 0; i < 4; ++i) mx4[i] = fmaxf(mx4[i], sc[h][nf][i]);
    float tm = fmaxf(fmaxf(mx4[0], mx4[1]), fmaxf(mx4[2], mx4[3]));
    tm = fmaxf(tm, __shfl_xor(tm, 16));
    tm = fmaxf(tm, __shfl_xor(tm, 32));
    float mn = fmaxf(m[h], tm);
    float alpha = __builtin_amdgcn_exp2f((m[h] - mn) * L2E);
    m[h] = mn;
    float mnL = mn * L2E;
    float ps = 0.f;
#pragma unroll
    for (int nf = 0; nf < 4; ++nf)
#pragma unroll
      for (int i = 0; i < 4; ++i) {
        float p = __builtin_amdgcn_exp2f(sc[h][nf][i] * L2E - mnL);
        ps += p;
        pf[h][nf][i] = (_Float16)p;
      }
    ps += __shfl_xor(ps, 16);
    ps += __shfl_xor(ps, 32);
    l[h] = l[h] * alpha + ps;
#pragma unroll
    for (int dt = 0; dt < 4; ++dt)
#pragma unroll
      for (int i = 0; i < 4; ++i) ot[h][dt][i] *= alpha;
  }
  __builtin_amdgcn_s_setprio(1);
#pragma unroll
  for (int nf = 0; nf < 4; ++nf)
#pragma unroll
    for (int dt = 0; dt < 4; ++dt) {
      f16x4 vf = *(const f16x4*)(Vs + (dt * 16 + lr) * LDP + nf * 16 + lg * 4);
      ot[0][dt] = MFMA16(vf, pf[0][nf], ot[0][dt]);
      ot[1][dt] = MFMA16(vf, pf[1][nf], ot[1][dt]);
    }
  __builtin_amdgcn_s_setprio(0);
}

__global__ __launch_bounds__(256) void attn_kernel(
    const _Float16* __restrict__ Q, const _Float16* __restrict__ K,
    const _Float16* __restrict__ VT,
    _Float16* __restrict__ PO0, _Float16* __restrict__ PO1,
    float2* __restrict__ ML) {
  __shared__ __align__(16) _Float16 Ks[2][64 * LDP];
  __shared__ __align__(16) _Float16 Vs[2][64 * LDP];
  int tid = threadIdx.x, lane = tid & 63, wid = tid >> 6;
  int b = blockIdx.z >> 1, half = blockIdx.z & 1;
  int qt = b ? (15 - (int)blockIdx.x) : (int)blockIdx.x;
  int hh = blockIdx.y;
  size_t hoff = (size_t)(b * 16 + hh) * 2048 * 64;
  const _Float16* Qh = Q + hoff;
  const _Float16* Kh = K + hoff;
  const _Float16* VTh = VT + hoff;
  int qwb = qt * 128 + wid * 32;
  int lr = lane & 15, lg = lane >> 4;

  // this half's tile range: [start, end) out of 2qt+2 tiles
  int start = half ? (qt + 1) : 0;
  int end = half ? (2 * qt + 2) : (qt + 1);

  f16x8 qb[2][2];
#pragma unroll
  for (int h = 0; h < 2; ++h) {
    const _Float16* qp = Qh + (size_t)(qwb + h * 16 + lr) * 64;
    qb[h][0] = *(const f16x8*)(qp + lg * 8);
    qb[h][1] = *(const f16x8*)(qp + 32 + lg * 8);
#pragma unroll
    for (int j = 0; j < 8; ++j) {      // fold 1/sqrt(64) into Q (exact: 2^-3)
      qb[h][0][j] *= (_Float16)0.125f;
      qb[h][1][j] *= (_Float16)0.125f;
    }
  }

  float m[2] = {-__builtin_inff(), -__builtin_inff()};
  float l[2] = {0.f, 0.f};
  f32x4 ot[2][4] = {};

  int r0 = tid >> 3, c0 = (tid & 7) * 8;
  int r1 = r0 + 32;
  // prologue: tile `start` -> buf 0
  {
    int kv = start * 64;
    int4 k0 = *(const int4*)(Kh + (size_t)(kv + r0) * 64 + c0);
    int4 k1 = *(const int4*)(Kh + (size_t)(kv + r1) * 64 + c0);
    int4 v0 = *(const int4*)(VTh + (size_t)r0 * 2048 + kv + c0);
    int4 v1 = *(const int4*)(VTh + (size_t)r1 * 2048 + kv + c0);
    *(int4*)(&Ks[0][0] + r0 * LDP + c0) = k0;
    *(int4*)(&Ks[0][0] + r1 * LDP + c0) = k1;
    *(int4*)(&Vs[0][0] + r0 * LDP + c0) = v0;
    *(int4*)(&Vs[0][0] + r1 * LDP + c0) = v1;
  }
  __syncthreads();

  int aw = qwb >> 6;                   // this wave's masked tile (global index)
  int4 rk0, rk1, rv0, rv1;
  for (int t = start; t < end; ++t) {
    int cur = (t - start) & 1;
    if (t + 1 < end) {                 // issue next tile's loads before compute
      int nkv = (t + 1) * 64;
      rk0 = *(const int4*)(Kh + (size_t)(nkv + r0) * 64 + c0);
      rk1 = *(const int4*)(Kh + (size_t)(nkv + r1) * 64 + c0);
      rv0 = *(const int4*)(VTh + (size_t)r0 * 2048 + nkv + c0);
      rv1 = *(const int4*)(VTh + (size_t)r1 * 2048 + nkv + c0);
    }
    if (t < aw)
      attn_tile32<false>(&Ks[cur][0], &Vs[cur][0], qb, t * 64, qwb, lr, lg, m, l, ot);
    else if (t == aw)
      attn_tile32<true>(&Ks[cur][0], &Vs[cur][0], qb, t * 64, qwb, lr, lg, m, l, ot);
    // t > aw: provable no-op; skip compute, keep barrier
    if (t + 1 < end) {
      *(int4*)(&Ks[cur ^ 1][0] + r0 * LDP + c0) = rk0;
      *(int4*)(&Ks[cur ^ 1][0] + r1 * LDP + c0) = rk1;
      *(int4*)(&Vs[cur ^ 1][0] + r0 * LDP + c0) = rv0;
      *(int4*)(&Vs[cur ^ 1][0] + r1 * LDP + c0) = rv1;
    }
    __syncthreads();
  }

  // write unnormalized O~ + (m, l) for this half
  _Float16* PO = half ? PO1 : PO0;
#pragma unroll
  for (int h = 0; h < 2; ++h) {
    int q = qwb + h * 16 + lr;
    if (lg == 0)                        // m,l uniform across the 4 row-lanes
      ML[(((size_t)(half * 2 + b) * 2048 + q) << 4) + hh] = float2{m[h], l[h]};
    _Float16* Oh = PO + ((size_t)b * 2048 + q) * 1024 + hh * 64;
#pragma unroll
    for (int dt = 0; dt < 4; ++dt) {
      f16x4 o;
#pragma unroll
      for (int i = 0; i < 4; ++i) o[i] = (_Float16)ot[h][dt][i];
      *(f16x4*)(Oh + dt * 16 + lg * 4) = o;
    }
  }
}

// ----------------------------------------------------- split-kv combine
// row = (b*2048+q)*16 + h; 8 lanes per row (chunk = 8 halves). PO1 == Oout
// (in-place): each thread reads its own elems then writes same address.
__global__ __launch_bounds__(256) void attn_combine(
    const _Float16* __restrict__ PO0, const _Float16* __restrict__ PO1,
    const float2* __restrict__ ML, _Float16* __restrict__ Oout) {
  const float L2E = 1.44269504f;
  int g = blockIdx.x * 256 + threadIdx.x;
  int row = g >> 3, chunk = g & 7;
  float2 a = ML[row];                  // half 0
  float2 c = ML[row + 65536];          // half 1
  float ms = fmaxf(a.x, c.x);
  float f0 = __builtin_amdgcn_exp2f((a.x - ms) * L2E);
  float f1 = __builtin_amdgcn_exp2f((c.x - ms) * L2E);
  float inv = 1.f / (f0 * a.y + f1 * c.y);
  f0 *= inv; f1 *= inv;
  int b = row >> 15, q = (row >> 4) & 2047, h = row & 15;
  size_t off = ((size_t)(b * 2048 + q) * 1024) + h * 64 + chunk * 8;
  f16x8 o0 = *(const f16x8*)(PO0 + off);
  f16x8 o1 = *(const f16x8*)(PO1 + off);
  f16x8 r;
#pragma unroll
  for (int j = 0; j < 8; ++j)
    r[j] = (_Float16)(f0 * (float)o0[j] + f1 * (float)o1[j]);
  *(f16x8*)(Oout + off) = r;
}

// ------------------------------------------------------------------- launch
extern "C" void kernel_launch(void* const* d_in, const int* in_sizes, int n_in,
                              void* d_out, int out_size, void* d_ws, size_t ws_size,
                              hipStream_t stream) {
  const float* x  = (const float*)d_in[0];
  const float* Wq = (const float*)d_in[1];
  const float* bq = (const float*)d_in[2];
  const float* Wk = (const float*)d_in[3];
  const float* bk = (const float*)d_in[4];
  const float* Wv = (const float*)d_in[5];
  const float* bv = (const float*)d_in[6];
  const float* Wo = (const float*)d_in[7];
  const float* bo = (const float*)d_in[8];
  float* out = (float*)d_out;

  _Float16* ws  = (_Float16*)d_ws;
  _Float16* xb  = ws;                 // dead after proj -> reused as PO0
  _Float16* wqb = ws + 4194304;
  _Float16* wkb = ws + 5242880;
  _Float16* wvb = ws + 6291456;       // dead after proj -> reused as ML
  _Float16* wob = ws + 7340032;
  _Float16* qw  = ws + 8388608;       // [B,H,S,64]
  _Float16* kw  = ws + 12582912;      // [B,H,S,64]
  _Float16* vtw = ws + 16777216;      // [B,H,64,S]
  _Float16* aw  = ws + 20971520;      // [B,S,1024] = PO1, combined in place

  _Float16* po0 = xb;                 // [B,S,1024] f16 (half-0 partial)
  float2*   ml  = (float2*)wvb;       // [2][B][S][16] float2 = 1 MiB

  convert_all<<<8192, 256, 0, stream>>>(x, Wq, Wk, Wv, Wo,
                                        xb, wqb, wkb, wvb, wob);

  proj_gemm<<<dim3(64, 8, 3), 256, 0, stream>>>(xb, wqb, wkb, wvb, bq, bk, bv,
                                                qw, kw, vtw);
  attn_kernel<<<dim3(16, 16, 4), 256, 0, stream>>>(qw, kw, vtw, po0, aw, ml);
  attn_combine<<<2048, 256, 0, stream>>>(po0, aw, ml, aw);
  out_gemm<<<dim3(64, 8), 256, 0, stream>>>(aw, wob, bo, out);
}

// Round 14
// 137.181 us; speedup vs baseline: 1.0033x; 1.0033x over previous
//
#include <hip/hip_runtime.h>

typedef _Float16 f16x8 __attribute__((ext_vector_type(8)));
typedef _Float16 f16x4 __attribute__((ext_vector_type(4)));
typedef float f32x4 __attribute__((ext_vector_type(4)));

#define MFMA32(a, b, c) __builtin_amdgcn_mfma_f32_16x16x32_f16(a, b, c, 0, 0, 0)
#define MFMA16(a, b, c) __builtin_amdgcn_mfma_f32_16x16x16f16(a, b, c, 0, 0, 0)

// ---------------------------------------------------------------- converts
__global__ __launch_bounds__(256) void convert_all(
    const float* __restrict__ x,
    const float* __restrict__ w0, const float* __restrict__ w1,
    const float* __restrict__ w2, const float* __restrict__ w3,
    _Float16* __restrict__ xb,
    _Float16* __restrict__ o0, _Float16* __restrict__ o1,
    _Float16* __restrict__ o2, _Float16* __restrict__ o3) {
  int chunk = blockIdx.x * 256 + threadIdx.x;
  const float* in;
  _Float16* out;
  int i;
  if (chunk < 1048576) {
    in = x; out = xb; i = chunk * 4;
  } else {
    int t = chunk - 1048576;
    int z = t >> 18;
    i = (t & 262143) * 4;
    in = (z == 0) ? w0 : (z == 1) ? w1 : (z == 2) ? w2 : w3;
    out = (z == 0) ? o0 : (z == 1) ? o1 : (z == 2) ? o2 : o3;
  }
  float4 v = *(const float4*)(in + i);
  f16x4 h;
  h.x = (_Float16)v.x; h.y = (_Float16)v.y; h.z = (_Float16)v.z; h.w = (_Float16)v.w;
  *(f16x4*)(out + i) = h;
}

// ---------------------------------------------------------------- GEMM core
// 64(M) x 128(N) tile, BK=64, 4 waves each computing 64x32 (acc 4x2).
__device__ __forceinline__ void gld_lds16(_Float16* l, const _Float16* g) {
  __builtin_amdgcn_global_load_lds(
      (const __attribute__((address_space(1))) unsigned int*)g,
      (__attribute__((address_space(3))) unsigned int*)l, 16, 0, 0);
}

__device__ __forceinline__ void stage64(_Float16* lds, const _Float16* g,
                                        int wid, int lane) {
#pragma unroll
  for (int j = 0; j < 2; ++j) {
    int blk = wid * 2 + j;
    int row = blk * 8 + (lane >> 3);
    int col = (lane & 7) * 8;
    gld_lds16(lds + blk * 512, g + (size_t)row * 1024 + col);
  }
}

__device__ __forceinline__ void stage128(_Float16* lds, const _Float16* g,
                                         int wid, int lane) {
#pragma unroll
  for (int j = 0; j < 4; ++j) {
    int blk = wid * 4 + j;
    int row = blk * 8 + (lane >> 3);
    int col = (lane & 7) * 8;
    gld_lds16(lds + blk * 512, g + (size_t)row * 1024 + col);
  }
}

__device__ __forceinline__ void gemm_core64(const _Float16* __restrict__ A,
                                            const _Float16* __restrict__ W,
                                            _Float16* As, _Float16* Bs,
                                            f32x4 acc[4][2], int m0, int n0, int tid) {
  int lane = tid & 63, wid = tid >> 6;
  int lr = lane & 15, lg = lane >> 4;
  int wn = wid * 32;
  for (int k0 = 0; k0 < 1024; k0 += 64) {
    __syncthreads();
    stage64(As, A + (size_t)m0 * 1024 + k0, wid, lane);
    stage128(Bs, W + (size_t)n0 * 1024 + k0, wid, lane);
    __syncthreads();
#pragma unroll
    for (int ks = 0; ks < 2; ++ks) {
      f16x8 af[4], bfv[2];
#pragma unroll
      for (int mf = 0; mf < 4; ++mf)
        af[mf] = *(const f16x8*)(As + (mf * 16 + lr) * 64 + ks * 32 + lg * 8);
#pragma unroll
      for (int nf = 0; nf < 2; ++nf)
        bfv[nf] = *(const f16x8*)(Bs + (wn + nf * 16 + lr) * 64 + ks * 32 + lg * 8);
#pragma unroll
      for (int mf = 0; mf < 4; ++mf)
#pragma unroll
        for (int nf = 0; nf < 2; ++nf)
          acc[mf][nf] = MFMA32(af[mf], bfv[nf], acc[mf][nf]);
    }
  }
}

// --------------------------------------------------- QKV projection GEMM
#define TRP 72  // Tr stride for 128x64 transpose buffer

__global__ __launch_bounds__(256) void proj_gemm(
    const _Float16* __restrict__ xb,
    const _Float16* __restrict__ wq, const _Float16* __restrict__ wk,
    const _Float16* __restrict__ wv,
    const float* __restrict__ bq, const float* __restrict__ bk,
    const float* __restrict__ bv,
    _Float16* __restrict__ qo, _Float16* __restrict__ ko, _Float16* __restrict__ vo) {
  __shared__ __align__(16) _Float16 smem[12288];   // As 4096 + Bs 8192 halves
  _Float16* As = smem;
  _Float16* Bs = smem + 4096;
  int z = blockIdx.z;
  const _Float16* W = (z == 0) ? wq : ((z == 1) ? wk : wv);
  const float* bias = (z == 0) ? bq : ((z == 1) ? bk : bv);
  int tid = threadIdx.x;
  int m0 = blockIdx.x * 64, n0 = blockIdx.y * 128;
  f32x4 acc[4][2] = {};
  gemm_core64(xb, W, As, Bs, acc, m0, n0, tid);

  int lane = tid & 63, wid = tid >> 6;
  int lr = lane & 15, lg = lane >> 4;
  int wn = wid * 32;

  if (z == 2) {
    _Float16* Tr = smem;                 // reuse As/Bs: 128*72 = 9216 <= 12288
    int b = m0 >> 11, s0 = m0 & 2047;
    __syncthreads();
#pragma unroll
    for (int nf = 0; nf < 2; ++nf) {
      int c = wn + nf * 16 + lr;
      float bb = bias[n0 + c];
#pragma unroll
      for (int mf = 0; mf < 4; ++mf)
#pragma unroll
        for (int i = 0; i < 4; ++i)
          Tr[c * TRP + mf * 16 + lg * 4 + i] = (_Float16)(acc[mf][nf][i] + bb);
    }
    __syncthreads();
#pragma unroll
    for (int j = 0; j < 4; ++j) {
      int cid = tid + 256 * j;
      int c = cid >> 3, seg = cid & 7;
      int cg = n0 + c, h = cg >> 6, hd = cg & 63;
      f16x8 v = *(const f16x8*)(Tr + c * TRP + seg * 8);
      *(f16x8*)(vo + ((size_t)(b * 16 + h) * 64 + hd) * 2048 + s0 + seg * 8) = v;
    }
  } else {
    _Float16* o = (z == 0) ? qo : ko;
#pragma unroll
    for (int nf = 0; nf < 2; ++nf) {
      int col = n0 + wn + nf * 16 + lr;
      float bb = bias[col];
      int h = col >> 6, hd = col & 63;
#pragma unroll
      for (int mf = 0; mf < 4; ++mf)
#pragma unroll
        for (int i = 0; i < 4; ++i) {
          int row = m0 + mf * 16 + lg * 4 + i;
          int b = row >> 11, s = row & 2047;
          o[((size_t)(b * 16 + h) * 2048 + s) * 64 + hd] = (_Float16)(acc[mf][nf][i] + bb);
        }
    }
  }
}

// --------------------------------------------------------- output GEMM (f32)
__global__ __launch_bounds__(256) void out_gemm(
    const _Float16* __restrict__ attn, const _Float16* __restrict__ wo,
    const float* __restrict__ bo, float* __restrict__ out) {
  __shared__ __align__(16) _Float16 smem[12288];
  _Float16* As = smem;
  _Float16* Bs = smem + 4096;
  int tid = threadIdx.x;
  int m0 = blockIdx.x * 64, n0 = blockIdx.y * 128;
  f32x4 acc[4][2] = {};
  gemm_core64(attn, wo, As, Bs, acc, m0, n0, tid);

  int lane = tid & 63, wid = tid >> 6;
  int lr = lane & 15, lg = lane >> 4;
  int wn = wid * 32;
#pragma unroll
  for (int nf = 0; nf < 2; ++nf) {
    int col = n0 + wn + nf * 16 + lr;
    float bb = bo[col];
#pragma unroll
    for (int mf = 0; mf < 4; ++mf)
#pragma unroll
      for (int i = 0; i < 4; ++i) {
        int row = m0 + mf * 16 + lg * 4 + i;
        out[(size_t)row * 1024 + col] = acc[mf][nf][i] + bb;
      }
  }
}

// --------------------------------------------------------- flash attention v12
// SPLIT-KV: grid (16,16,4) = 1024 blocks (z = b*2 + half); each block does
// half of its (qt,h,b)'s kv tiles -> 4 blocks/CU, 4 waves/SIMD (was 2).
// Per-tile math + dbuf loop verbatim r12 (passed). Final write: unnormalized
// O~ (f16) + per-row (m,l); a combine kernel merges the two halves.
#define LDP 72  // padded LDS stride (halves)

template <bool MASK>
__device__ __forceinline__ void attn_tile32(const _Float16* Ks, const _Float16* Vs,
                                            const f16x8 qb[2][2], int kv0, int qwb,
                                            int lr, int lg,
                                            float m[2], float l[2], f32x4 ot[2][4]) {
  const float L2E = 1.44269504f;
  const float NINF = -__builtin_inff();
  f16x8 kf0[4], kf1[4];
#pragma unroll
  for (int nf = 0; nf < 4; ++nf) {
    kf0[nf] = *(const f16x8*)(Ks + (nf * 16 + lr) * LDP + lg * 8);
    kf1[nf] = *(const f16x8*)(Ks + (nf * 16 + lr) * LDP + 32 + lg * 8);
  }
  f32x4 sc[2][4];
  __builtin_amdgcn_s_setprio(1);
#pragma unroll
  for (int h = 0; h < 2; ++h)
#pragma unroll
    for (int nf = 0; nf < 4; ++nf) {
      f32x4 z = {0.f, 0.f, 0.f, 0.f};
      z = MFMA32(kf0[nf], qb[h][0], z);
      z = MFMA32(kf1[nf], qb[h][1], z);
      sc[h][nf] = z;
    }
  __builtin_amdgcn_s_setprio(0);
  if (MASK) {
#pragma unroll
    for (int h = 0; h < 2; ++h) {
      int qg = qwb + h * 16 + lr;
#pragma unroll
      for (int nf = 0; nf < 4; ++nf)
#pragma unroll
        for (int i = 0; i < 4; ++i) {
          int kg = kv0 + nf * 16 + lg * 4 + i;
          sc[h][nf][i] = (kg <= qg) ? sc[h][nf][i] : NINF;
        }
    }
  }
  f16x4 pf[2][4];
#pragma unroll
  for (int h = 0; h < 2; ++h) {
    f32x4 mx4 = sc[h][0];
#pragma unroll
    for (int nf = 1; nf < 4; ++nf)
#pragma unroll
      for (int i = 0; i < 4; ++i) mx4[i] = fmaxf(mx4[i], sc[h][nf][i]);
    float tm = fmaxf(fmaxf(mx4[0], mx4[1]), fmaxf(mx4[2], mx4[3]));
    tm = fmaxf(tm, __shfl_xor(tm, 16));
    tm = fmaxf(tm, __shfl_xor(tm, 32));
    float mn = fmaxf(m[h], tm);
    float alpha = __builtin_amdgcn_exp2f((m[h] - mn) * L2E);
    m[h] = mn;
    float mnL = mn * L2E;
    float ps = 0.f;
#pragma unroll
    for (int nf = 0; nf < 4; ++nf)
#pragma unroll
      for (int i = 0; i < 4; ++i) {
        float p = __builtin_amdgcn_exp2f(sc[h][nf][i] * L2E - mnL);
        ps += p;
        pf[h][nf][i] = (_Float16)p;
      }
    ps += __shfl_xor(ps, 16);
    ps += __shfl_xor(ps, 32);
    l[h] = l[h] * alpha + ps;
#pragma unroll
    for (int dt = 0; dt < 4; ++dt)
#pragma unroll
      for (int i = 0; i < 4; ++i) ot[h][dt][i] *= alpha;
  }
  __builtin_amdgcn_s_setprio(1);
#pragma unroll
  for (int nf = 0; nf < 4; ++nf)
#pragma unroll
    for (int dt = 0; dt < 4; ++dt) {
      f16x4 vf = *(const f16x4*)(Vs + (dt * 16 + lr) * LDP + nf * 16 + lg * 4);
      ot[0][dt] = MFMA16(vf, pf[0][nf], ot[0][dt]);
      ot[1][dt] = MFMA16(vf, pf[1][nf], ot[1][dt]);
    }
  __builtin_amdgcn_s_setprio(0);
}

__global__ __launch_bounds__(256) void attn_kernel(
    const _Float16* __restrict__ Q, const _Float16* __restrict__ K,
    const _Float16* __restrict__ VT,
    _Float16* __restrict__ PO0, _Float16* __restrict__ PO1,
    float2* __restrict__ ML) {
  __shared__ __align__(16) _Float16 Ks[2][64 * LDP];
  __shared__ __align__(16) _Float16 Vs[2][64 * LDP];
  int tid = threadIdx.x, lane = tid & 63, wid = tid >> 6;
  int b = blockIdx.z >> 1, half = blockIdx.z & 1;
  int qt = b ? (15 - (int)blockIdx.x) : (int)blockIdx.x;
  int hh = blockIdx.y;
  size_t hoff = (size_t)(b * 16 + hh) * 2048 * 64;
  const _Float16* Qh = Q + hoff;
  const _Float16* Kh = K + hoff;
  const _Float16* VTh = VT + hoff;
  int qwb = qt * 128 + wid * 32;
  int lr = lane & 15, lg = lane >> 4;

  // this half's tile range: [start, end) out of 2qt+2 tiles
  int start = half ? (qt + 1) : 0;
  int end = half ? (2 * qt + 2) : (qt + 1);

  f16x8 qb[2][2];
#pragma unroll
  for (int h = 0; h < 2; ++h) {
    const _Float16* qp = Qh + (size_t)(qwb + h * 16 + lr) * 64;
    qb[h][0] = *(const f16x8*)(qp + lg * 8);
    qb[h][1] = *(const f16x8*)(qp + 32 + lg * 8);
#pragma unroll
    for (int j = 0; j < 8; ++j) {      // fold 1/sqrt(64) into Q (exact: 2^-3)
      qb[h][0][j] *= (_Float16)0.125f;
      qb[h][1][j] *= (_Float16)0.125f;
    }
  }

  float m[2] = {-__builtin_inff(), -__builtin_inff()};
  float l[2] = {0.f, 0.f};
  f32x4 ot[2][4] = {};

  int r0 = tid >> 3, c0 = (tid & 7) * 8;
  int r1 = r0 + 32;
  // prologue: tile `start` -> buf 0
  {
    int kv = start * 64;
    int4 k0 = *(const int4*)(Kh + (size_t)(kv + r0) * 64 + c0);
    int4 k1 = *(const int4*)(Kh + (size_t)(kv + r1) * 64 + c0);
    int4 v0 = *(const int4*)(VTh + (size_t)r0 * 2048 + kv + c0);
    int4 v1 = *(const int4*)(VTh + (size_t)r1 * 2048 + kv + c0);
    *(int4*)(&Ks[0][0] + r0 * LDP + c0) = k0;
    *(int4*)(&Ks[0][0] + r1 * LDP + c0) = k1;
    *(int4*)(&Vs[0][0] + r0 * LDP + c0) = v0;
    *(int4*)(&Vs[0][0] + r1 * LDP + c0) = v1;
  }
  __syncthreads();

  int aw = qwb >> 6;                   // this wave's masked tile (global index)
  int4 rk0, rk1, rv0, rv1;
  for (int t = start; t < end; ++t) {
    int cur = (t - start) & 1;
    if (t + 1 < end) {                 // issue next tile's loads before compute
      int nkv = (t + 1) * 64;
      rk0 = *(const int4*)(Kh + (size_t)(nkv + r0) * 64 + c0);
      rk1 = *(const int4*)(Kh + (size_t)(nkv + r1) * 64 + c0);
      rv0 = *(const int4*)(VTh + (size_t)r0 * 2048 + nkv + c0);
      rv1 = *(const int4*)(VTh + (size_t)r1 * 2048 + nkv + c0);
    }
    if (t < aw)
      attn_tile32<false>(&Ks[cur][0], &Vs[cur][0], qb, t * 64, qwb, lr, lg, m, l, ot);
    else if (t == aw)
      attn_tile32<true>(&Ks[cur][0], &Vs[cur][0], qb, t * 64, qwb, lr, lg, m, l, ot);
    // t > aw: provable no-op; skip compute, keep barrier
    if (t + 1 < end) {
      *(int4*)(&Ks[cur ^ 1][0] + r0 * LDP + c0) = rk0;
      *(int4*)(&Ks[cur ^ 1][0] + r1 * LDP + c0) = rk1;
      *(int4*)(&Vs[cur ^ 1][0] + r0 * LDP + c0) = rv0;
      *(int4*)(&Vs[cur ^ 1][0] + r1 * LDP + c0) = rv1;
    }
    __syncthreads();
  }

  // write unnormalized O~ + (m, l) for this half
  _Float16* PO = half ? PO1 : PO0;
#pragma unroll
  for (int h = 0; h < 2; ++h) {
    int q = qwb + h * 16 + lr;
    if (lg == 0)                        // m,l uniform across the 4 row-lanes
      ML[(((size_t)(half * 2 + b) * 2048 + q) << 4) + hh] = float2{m[h], l[h]};
    _Float16* Oh = PO + ((size_t)b * 2048 + q) * 1024 + hh * 64;
#pragma unroll
    for (int dt = 0; dt < 4; ++dt) {
      f16x4 o;
#pragma unroll
      for (int i = 0; i < 4; ++i) o[i] = (_Float16)ot[h][dt][i];
      *(f16x4*)(Oh + dt * 16 + lg * 4) = o;
    }
  }
}

// ----------------------------------------------------- split-kv combine
// row = (b*2048+q)*16 + h; 8 lanes per row (chunk = 8 halves). PO1 == Oout
// (in-place): each thread reads its own elems then writes same address.
__global__ __launch_bounds__(256) void attn_combine(
    const _Float16* __restrict__ PO0, const _Float16* __restrict__ PO1,
    const float2* __restrict__ ML, _Float16* __restrict__ Oout) {
  const float L2E = 1.44269504f;
  int g = blockIdx.x * 256 + threadIdx.x;
  int row = g >> 3, chunk = g & 7;
  float2 a = ML[row];                  // half 0
  float2 c = ML[row + 65536];          // half 1
  float ms = fmaxf(a.x, c.x);
  float f0 = __builtin_amdgcn_exp2f((a.x - ms) * L2E);
  float f1 = __builtin_amdgcn_exp2f((c.x - ms) * L2E);
  float inv = 1.f / (f0 * a.y + f1 * c.y);
  f0 *= inv; f1 *= inv;
  int b = row >> 15, q = (row >> 4) & 2047, h = row & 15;
  size_t off = ((size_t)(b * 2048 + q) * 1024) + h * 64 + chunk * 8;
  f16x8 o0 = *(const f16x8*)(PO0 + off);
  f16x8 o1 = *(const f16x8*)(PO1 + off);
  f16x8 r;
#pragma unroll
  for (int j = 0; j < 8; ++j)
    r[j] = (_Float16)(f0 * (float)o0[j] + f1 * (float)o1[j]);
  *(f16x8*)(Oout + off) = r;
}

// ------------------------------------------------------------------- launch
extern "C" void kernel_launch(void* const* d_in, const int* in_sizes, int n_in,
                              void* d_out, int out_size, void* d_ws, size_t ws_size,
                              hipStream_t stream) {
  const float* x  = (const float*)d_in[0];
  const float* Wq = (const float*)d_in[1];
  const float* bq = (const float*)d_in[2];
  const float* Wk = (const float*)d_in[3];
  const float* bk = (const float*)d_in[4];
  const float* Wv = (const float*)d_in[5];
  const float* bv = (const float*)d_in[6];
  const float* Wo = (const float*)d_in[7];
  const float* bo = (const float*)d_in[8];
  float* out = (float*)d_out;

  _Float16* ws  = (_Float16*)d_ws;
  _Float16* xb  = ws;                 // dead after proj -> reused as PO0
  _Float16* wqb = ws + 4194304;
  _Float16* wkb = ws + 5242880;
  _Float16* wvb = ws + 6291456;       // dead after proj -> reused as ML
  _Float16* wob = ws + 7340032;
  _Float16* qw  = ws + 8388608;       // [B,H,S,64]
  _Float16* kw  = ws + 12582912;      // [B,H,S,64]
  _Float16* vtw = ws + 16777216;      // [B,H,64,S]
  _Float16* aw  = ws + 20971520;      // [B,S,1024] = PO1, combined in place

  _Float16* po0 = xb;                 // [B,S,1024] f16 (half-0 partial)
  float2*   ml  = (float2*)wvb;       // [2][B][S][16] float2 = 1 MiB

  convert_all<<<8192, 256, 0, stream>>>(x, Wq, Wk, Wv, Wo,
                                        xb, wqb, wkb, wvb, wob);

  proj_gemm<<<dim3(64, 8, 3), 256, 0, stream>>>(xb, wqb, wkb, wvb, bq, bk, bv,
                                                qw, kw, vtw);
  attn_kernel<<<dim3(16, 16, 4), 256, 0, stream>>>(qw, kw, vtw, po0, aw, ml);
  attn_combine<<<2048, 256, 0, stream>>>(po0, aw, ml, aw);
  out_gemm<<<dim3(64, 8), 256, 0, stream>>>(aw, wob, bo, out);
}

// Round 16
// 123.447 us; speedup vs baseline: 1.1149x; 1.1113x over previous
//
#include <hip/hip_runtime.h>

typedef _Float16 f16x8 __attribute__((ext_vector_type(8)));
typedef _Float16 f16x4 __attribute__((ext_vector_type(4)));
typedef float f32x4 __attribute__((ext_vector_type(4)));

#define MFMA32(a, b, c) __builtin_amdgcn_mfma_f32_16x16x32_f16(a, b, c, 0, 0, 0)
#define MFMA16(a, b, c) __builtin_amdgcn_mfma_f32_16x16x16f16(a, b, c, 0, 0, 0)

// ---------------------------------------------------------------- converts
__global__ __launch_bounds__(256) void convert_all(
    const float* __restrict__ x,
    const float* __restrict__ w0, const float* __restrict__ w1,
    const float* __restrict__ w2, const float* __restrict__ w3,
    _Float16* __restrict__ xb,
    _Float16* __restrict__ o0, _Float16* __restrict__ o1,
    _Float16* __restrict__ o2, _Float16* __restrict__ o3) {
  int chunk = blockIdx.x * 256 + threadIdx.x;
  const float* in;
  _Float16* out;
  int i;
  if (chunk < 1048576) {
    in = x; out = xb; i = chunk * 4;
  } else {
    int t = chunk - 1048576;
    int z = t >> 18;
    i = (t & 262143) * 4;
    in = (z == 0) ? w0 : (z == 1) ? w1 : (z == 2) ? w2 : w3;
    out = (z == 0) ? o0 : (z == 1) ? o1 : (z == 2) ? o2 : o3;
  }
  float4 v = *(const float4*)(in + i);
  f16x4 h;
  h.x = (_Float16)v.x; h.y = (_Float16)v.y; h.z = (_Float16)v.z; h.w = (_Float16)v.w;
  *(f16x4*)(out + i) = h;
}

// ---------------------------------------------------------------- GEMM core
// 64(M) x 128(N) tile, BK=64, 4 waves each computing 64x32 (acc 4x2).
// Single-buffer, 2 barriers per K-step — the r9-r14 proven-correct structure
// (the r15 2-phase dbuf variant raced; reverted per post-timing divergence).
// Grid (64, n, z): XCD = bx%8 -> all n/z blocks of an A-panel share one L2.
__device__ __forceinline__ void gld_lds16(_Float16* l, const _Float16* g) {
  __builtin_amdgcn_global_load_lds(
      (const __attribute__((address_space(1))) unsigned int*)g,
      (__attribute__((address_space(3))) unsigned int*)l, 16, 0, 0);
}

__device__ __forceinline__ void stage64(_Float16* lds, const _Float16* g,
                                        int wid, int lane) {
#pragma unroll
  for (int j = 0; j < 2; ++j) {
    int blk = wid * 2 + j;
    int row = blk * 8 + (lane >> 3);
    int col = (lane & 7) * 8;
    gld_lds16(lds + blk * 512, g + (size_t)row * 1024 + col);
  }
}

__device__ __forceinline__ void stage128(_Float16* lds, const _Float16* g,
                                         int wid, int lane) {
#pragma unroll
  for (int j = 0; j < 4; ++j) {
    int blk = wid * 4 + j;
    int row = blk * 8 + (lane >> 3);
    int col = (lane & 7) * 8;
    gld_lds16(lds + blk * 512, g + (size_t)row * 1024 + col);
  }
}

__device__ __forceinline__ void gemm_core64(const _Float16* __restrict__ A,
                                            const _Float16* __restrict__ W,
                                            _Float16* As, _Float16* Bs,
                                            f32x4 acc[4][2], int m0, int n0, int tid) {
  int lane = tid & 63, wid = tid >> 6;
  int lr = lane & 15, lg = lane >> 4;
  int wn = wid * 32;
  for (int k0 = 0; k0 < 1024; k0 += 64) {
    __syncthreads();
    stage64(As, A + (size_t)m0 * 1024 + k0, wid, lane);
    stage128(Bs, W + (size_t)n0 * 1024 + k0, wid, lane);
    __syncthreads();
#pragma unroll
    for (int ks = 0; ks < 2; ++ks) {
      f16x8 af[4], bfv[2];
#pragma unroll
      for (int mf = 0; mf < 4; ++mf)
        af[mf] = *(const f16x8*)(As + (mf * 16 + lr) * 64 + ks * 32 + lg * 8);
#pragma unroll
      for (int nf = 0; nf < 2; ++nf)
        bfv[nf] = *(const f16x8*)(Bs + (wn + nf * 16 + lr) * 64 + ks * 32 + lg * 8);
#pragma unroll
      for (int mf = 0; mf < 4; ++mf)
#pragma unroll
        for (int nf = 0; nf < 2; ++nf)
          acc[mf][nf] = MFMA32(af[mf], bfv[nf], acc[mf][nf]);
    }
  }
}

// --------------------------------------------------- QKV projection GEMM
#define TRP 72  // Tr stride for 128x64 transpose buffer

__global__ __launch_bounds__(256) void proj_gemm(
    const _Float16* __restrict__ xb,
    const _Float16* __restrict__ wq, const _Float16* __restrict__ wk,
    const _Float16* __restrict__ wv,
    const float* __restrict__ bq, const float* __restrict__ bk,
    const float* __restrict__ bv,
    _Float16* __restrict__ qo, _Float16* __restrict__ ko, _Float16* __restrict__ vo) {
  __shared__ __align__(16) _Float16 smem[12288];   // As 4096 + Bs 8192 halves
  _Float16* As = smem;
  _Float16* Bs = smem + 4096;
  int z = blockIdx.z;
  const _Float16* W = (z == 0) ? wq : ((z == 1) ? wk : wv);
  const float* bias = (z == 0) ? bq : ((z == 1) ? bk : bv);
  int tid = threadIdx.x;
  int m0 = blockIdx.x * 64, n0 = blockIdx.y * 128;
  f32x4 acc[4][2] = {};
  gemm_core64(xb, W, As, Bs, acc, m0, n0, tid);

  int lane = tid & 63, wid = tid >> 6;
  int lr = lane & 15, lg = lane >> 4;
  int wn = wid * 32;

  if (z == 2) {
    _Float16* Tr = smem;                 // reuse As/Bs: 128*72 = 9216 <= 12288
    int b = m0 >> 11, s0 = m0 & 2047;
    __syncthreads();
#pragma unroll
    for (int nf = 0; nf < 2; ++nf) {
      int c = wn + nf * 16 + lr;
      float bb = bias[n0 + c];
#pragma unroll
      for (int mf = 0; mf < 4; ++mf)
#pragma unroll
        for (int i = 0; i < 4; ++i)
          Tr[c * TRP + mf * 16 + lg * 4 + i] = (_Float16)(acc[mf][nf][i] + bb);
    }
    __syncthreads();
#pragma unroll
    for (int j = 0; j < 4; ++j) {
      int cid = tid + 256 * j;
      int c = cid >> 3, seg = cid & 7;
      int cg = n0 + c, h = cg >> 6, hd = cg & 63;
      f16x8 v = *(const f16x8*)(Tr + c * TRP + seg * 8);
      *(f16x8*)(vo + ((size_t)(b * 16 + h) * 64 + hd) * 2048 + s0 + seg * 8) = v;
    }
  } else {
    _Float16* o = (z == 0) ? qo : ko;
#pragma unroll
    for (int nf = 0; nf < 2; ++nf) {
      int col = n0 + wn + nf * 16 + lr;
      float bb = bias[col];
      int h = col >> 6, hd = col & 63;
#pragma unroll
      for (int mf = 0; mf < 4; ++mf)
#pragma unroll
        for (int i = 0; i < 4; ++i) {
          int row = m0 + mf * 16 + lg * 4 + i;
          int b = row >> 11, s = row & 2047;
          o[((size_t)(b * 16 + h) * 2048 + s) * 64 + hd] = (_Float16)(acc[mf][nf][i] + bb);
        }
    }
  }
}

// --------------------------------------------------------- output GEMM (f32)
__global__ __launch_bounds__(256) void out_gemm(
    const _Float16* __restrict__ attn, const _Float16* __restrict__ wo,
    const float* __restrict__ bo, float* __restrict__ out) {
  __shared__ __align__(16) _Float16 smem[12288];
  _Float16* As = smem;
  _Float16* Bs = smem + 4096;
  int tid = threadIdx.x;
  int m0 = blockIdx.x * 64, n0 = blockIdx.y * 128;
  f32x4 acc[4][2] = {};
  gemm_core64(attn, wo, As, Bs, acc, m0, n0, tid);

  int lane = tid & 63, wid = tid >> 6;
  int lr = lane & 15, lg = lane >> 4;
  int wn = wid * 32;
#pragma unroll
  for (int nf = 0; nf < 2; ++nf) {
    int col = n0 + wn + nf * 16 + lr;
    float bb = bo[col];
#pragma unroll
    for (int mf = 0; mf < 4; ++mf)
#pragma unroll
      for (int i = 0; i < 4; ++i) {
        int row = m0 + mf * 16 + lg * 4 + i;
        out[(size_t)row * 1024 + col] = acc[mf][nf][i] + bb;
      }
  }
}

// --------------------------------------------------------- flash attention v13
// r12-exact (best attn config, 56.2us) with ONE isolated delta: setprio
// REMOVED (m190: setprio hurts barrier-synced multi-wave lockstep kernels).
#define LDP 72  // padded LDS stride (halves)

template <bool MASK>
__device__ __forceinline__ void attn_tile32(const _Float16* Ks, const _Float16* Vs,
                                            const f16x8 qb[2][2], int kv0, int qwb,
                                            int lr, int lg,
                                            float m[2], float l[2], f32x4 ot[2][4]) {
  const float L2E = 1.44269504f;
  const float NINF = -__builtin_inff();
  f16x8 kf0[4], kf1[4];
#pragma unroll
  for (int nf = 0; nf < 4; ++nf) {
    kf0[nf] = *(const f16x8*)(Ks + (nf * 16 + lr) * LDP + lg * 8);
    kf1[nf] = *(const f16x8*)(Ks + (nf * 16 + lr) * LDP + 32 + lg * 8);
  }
  f32x4 sc[2][4];
#pragma unroll
  for (int h = 0; h < 2; ++h)
#pragma unroll
    for (int nf = 0; nf < 4; ++nf) {
      f32x4 z = {0.f, 0.f, 0.f, 0.f};
      z = MFMA32(kf0[nf], qb[h][0], z);
      z = MFMA32(kf1[nf], qb[h][1], z);
      sc[h][nf] = z;
    }
  if (MASK) {
#pragma unroll
    for (int h = 0; h < 2; ++h) {
      int qg = qwb + h * 16 + lr;
#pragma unroll
      for (int nf = 0; nf < 4; ++nf)
#pragma unroll
        for (int i = 0; i < 4; ++i) {
          int kg = kv0 + nf * 16 + lg * 4 + i;
          sc[h][nf][i] = (kg <= qg) ? sc[h][nf][i] : NINF;
        }
    }
  }
  f16x4 pf[2][4];
#pragma unroll
  for (int h = 0; h < 2; ++h) {
    f32x4 mx4 = sc[h][0];
#pragma unroll
    for (int nf = 1; nf < 4; ++nf)
#pragma unroll
      for (int i = 0; i < 4; ++i) mx4[i] = fmaxf(mx4[i], sc[h][nf][i]);
    float tm = fmaxf(fmaxf(mx4[0], mx4[1]), fmaxf(mx4[2], mx4[3]));
    tm = fmaxf(tm, __shfl_xor(tm, 16));
    tm = fmaxf(tm, __shfl_xor(tm, 32));
    float mn = fmaxf(m[h], tm);
    float alpha = __builtin_amdgcn_exp2f((m[h] - mn) * L2E);
    m[h] = mn;
    float mnL = mn * L2E;
    float ps = 0.f;
#pragma unroll
    for (int nf = 0; nf < 4; ++nf)
#pragma unroll
      for (int i = 0; i < 4; ++i) {
        float p = __builtin_amdgcn_exp2f(sc[h][nf][i] * L2E - mnL);
        ps += p;
        pf[h][nf][i] = (_Float16)p;
      }
    ps += __shfl_xor(ps, 16);
    ps += __shfl_xor(ps, 32);
    l[h] = l[h] * alpha + ps;
#pragma unroll
    for (int dt = 0; dt < 4; ++dt)
#pragma unroll
      for (int i = 0; i < 4; ++i) ot[h][dt][i] *= alpha;
  }
#pragma unroll
  for (int nf = 0; nf < 4; ++nf)
#pragma unroll
    for (int dt = 0; dt < 4; ++dt) {
      f16x4 vf = *(const f16x4*)(Vs + (dt * 16 + lr) * LDP + nf * 16 + lg * 4);
      ot[0][dt] = MFMA16(vf, pf[0][nf], ot[0][dt]);
      ot[1][dt] = MFMA16(vf, pf[1][nf], ot[1][dt]);
    }
}

__global__ __launch_bounds__(256) void attn_kernel(
    const _Float16* __restrict__ Q, const _Float16* __restrict__ K,
    const _Float16* __restrict__ VT, _Float16* __restrict__ O) {
  __shared__ __align__(16) _Float16 Ks[2][64 * LDP];
  __shared__ __align__(16) _Float16 Vs[2][64 * LDP];
  int tid = threadIdx.x, lane = tid & 63, wid = tid >> 6;
  int qt = blockIdx.z ? (15 - (int)blockIdx.x) : (int)blockIdx.x;
  int hh = blockIdx.y, b = blockIdx.z;
  size_t hoff = (size_t)(b * 16 + hh) * 2048 * 64;
  const _Float16* Qh = Q + hoff;
  const _Float16* Kh = K + hoff;
  const _Float16* VTh = VT + hoff;
  int qwb = qt * 128 + wid * 32;
  int lr = lane & 15, lg = lane >> 4;

  f16x8 qb[2][2];
#pragma unroll
  for (int h = 0; h < 2; ++h) {
    const _Float16* qp = Qh + (size_t)(qwb + h * 16 + lr) * 64;
    qb[h][0] = *(const f16x8*)(qp + lg * 8);
    qb[h][1] = *(const f16x8*)(qp + 32 + lg * 8);
#pragma unroll
    for (int j = 0; j < 8; ++j) {      // fold 1/sqrt(64) into Q (exact: 2^-3)
      qb[h][0][j] *= (_Float16)0.125f;
      qb[h][1][j] *= (_Float16)0.125f;
    }
  }

  float m[2] = {-__builtin_inff(), -__builtin_inff()};
  float l[2] = {0.f, 0.f};
  f32x4 ot[2][4] = {};

  int r0 = tid >> 3, c0 = (tid & 7) * 8;
  int r1 = r0 + 32;
  // prologue: tile 0 -> buf 0
  int4 rk0 = *(const int4*)(Kh + (size_t)r0 * 64 + c0);
  int4 rk1 = *(const int4*)(Kh + (size_t)r1 * 64 + c0);
  int4 rv0 = *(const int4*)(VTh + (size_t)r0 * 2048 + c0);
  int4 rv1 = *(const int4*)(VTh + (size_t)r1 * 2048 + c0);
  *(int4*)(&Ks[0][0] + r0 * LDP + c0) = rk0;
  *(int4*)(&Ks[0][0] + r1 * LDP + c0) = rk1;
  *(int4*)(&Vs[0][0] + r0 * LDP + c0) = rv0;
  *(int4*)(&Vs[0][0] + r1 * LDP + c0) = rv1;
  __syncthreads();

  int aw = qwb >> 6;                   // first masked tile for this wave
  int ntiles = 2 * qt + 2;
  for (int t = 0; t < ntiles; ++t) {
    int cur = t & 1;
    if (t + 1 < ntiles) {              // issue next tile's loads before compute
      int nkv = (t + 1) * 64;
      rk0 = *(const int4*)(Kh + (size_t)(nkv + r0) * 64 + c0);
      rk1 = *(const int4*)(Kh + (size_t)(nkv + r1) * 64 + c0);
      rv0 = *(const int4*)(VTh + (size_t)r0 * 2048 + nkv + c0);
      rv1 = *(const int4*)(VTh + (size_t)r1 * 2048 + nkv + c0);
    }
    if (t < aw)
      attn_tile32<false>(&Ks[cur][0], &Vs[cur][0], qb, t * 64, qwb, lr, lg, m, l, ot);
    else if (t == aw)
      attn_tile32<true>(&Ks[cur][0], &Vs[cur][0], qb, t * 64, qwb, lr, lg, m, l, ot);
    // t > aw: provable no-op (all masked); skip compute, keep barriers
    if (t + 1 < ntiles) {
      *(int4*)(&Ks[cur ^ 1][0] + r0 * LDP + c0) = rk0;
      *(int4*)(&Ks[cur ^ 1][0] + r1 * LDP + c0) = rk1;
      *(int4*)(&Vs[cur ^ 1][0] + r0 * LDP + c0) = rv0;
      *(int4*)(&Vs[cur ^ 1][0] + r1 * LDP + c0) = rv1;
    }
    __syncthreads();
  }

#pragma unroll
  for (int h = 0; h < 2; ++h) {
    float inv = 1.f / l[h];
    _Float16* Oh = O + ((size_t)b * 2048 + qwb + h * 16 + lr) * 1024 + hh * 64;
#pragma unroll
    for (int dt = 0; dt < 4; ++dt) {
      f16x4 o;
#pragma unroll
      for (int i = 0; i < 4; ++i) o[i] = (_Float16)(ot[h][dt][i] * inv);
      *(f16x4*)(Oh + dt * 16 + lg * 4) = o;
    }
  }
}

// ------------------------------------------------------------------- launch
extern "C" void kernel_launch(void* const* d_in, const int* in_sizes, int n_in,
                              void* d_out, int out_size, void* d_ws, size_t ws_size,
                              hipStream_t stream) {
  const float* x  = (const float*)d_in[0];
  const float* Wq = (const float*)d_in[1];
  const float* bq = (const float*)d_in[2];
  const float* Wk = (const float*)d_in[3];
  const float* bk = (const float*)d_in[4];
  const float* Wv = (const float*)d_in[5];
  const float* bv = (const float*)d_in[6];
  const float* Wo = (const float*)d_in[7];
  const float* bo = (const float*)d_in[8];
  float* out = (float*)d_out;

  _Float16* ws  = (_Float16*)d_ws;
  _Float16* xb  = ws;
  _Float16* wqb = ws + 4194304;
  _Float16* wkb = ws + 5242880;
  _Float16* wvb = ws + 6291456;
  _Float16* wob = ws + 7340032;
  _Float16* qw  = ws + 8388608;       // [B,H,S,64]
  _Float16* kw  = ws + 12582912;      // [B,H,S,64]
  _Float16* vtw = ws + 16777216;      // [B,H,64,S]
  _Float16* aw  = ws + 20971520;      // [B,S,1024]

  convert_all<<<8192, 256, 0, stream>>>(x, Wq, Wk, Wv, Wo,
                                        xb, wqb, wkb, wvb, wob);

  proj_gemm<<<dim3(64, 8, 3), 256, 0, stream>>>(xb, wqb, wkb, wvb, bq, bk, bv,
                                                qw, kw, vtw);
  attn_kernel<<<dim3(16, 16, 2), 256, 0, stream>>>(qw, kw, vtw, aw);
  out_gemm<<<dim3(64, 8), 256, 0, stream>>>(aw, wob, bo, out);
}

// Round 17
// 122.978 us; speedup vs baseline: 1.1192x; 1.0038x over previous
//
#include <hip/hip_runtime.h>

typedef _Float16 f16x8 __attribute__((ext_vector_type(8)));
typedef _Float16 f16x4 __attribute__((ext_vector_type(4)));
typedef float f32x4 __attribute__((ext_vector_type(4)));

#define MFMA32(a, b, c) __builtin_amdgcn_mfma_f32_16x16x32_f16(a, b, c, 0, 0, 0)
#define MFMA16(a, b, c) __builtin_amdgcn_mfma_f32_16x16x16f16(a, b, c, 0, 0, 0)

// ---------------------------------------------------------------- converts
__global__ __launch_bounds__(256) void convert_all(
    const float* __restrict__ x,
    const float* __restrict__ w0, const float* __restrict__ w1,
    const float* __restrict__ w2, const float* __restrict__ w3,
    _Float16* __restrict__ xb,
    _Float16* __restrict__ o0, _Float16* __restrict__ o1,
    _Float16* __restrict__ o2, _Float16* __restrict__ o3) {
  int chunk = blockIdx.x * 256 + threadIdx.x;
  const float* in;
  _Float16* out;
  int i;
  if (chunk < 1048576) {
    in = x; out = xb; i = chunk * 4;
  } else {
    int t = chunk - 1048576;
    int z = t >> 18;
    i = (t & 262143) * 4;
    in = (z == 0) ? w0 : (z == 1) ? w1 : (z == 2) ? w2 : w3;
    out = (z == 0) ? o0 : (z == 1) ? o1 : (z == 2) ? o2 : o3;
  }
  float4 v = *(const float4*)(in + i);
  f16x4 h;
  h.x = (_Float16)v.x; h.y = (_Float16)v.y; h.z = (_Float16)v.z; h.w = (_Float16)v.w;
  *(f16x4*)(out + i) = h;
}

// ---------------------------------------------------------------- GEMM core
// 64(M) x 128(N) tile, BK=64, 4 waves each computing 64x32 (acc 4x2).
// Single-buffer, 2 barriers per K-step (r9-r16 proven; r15 dbuf raced).
// Grid (64, n, z): XCD = bx%8 -> all n/z blocks of an A-panel share one L2.
__device__ __forceinline__ void gld_lds16(_Float16* l, const _Float16* g) {
  __builtin_amdgcn_global_load_lds(
      (const __attribute__((address_space(1))) unsigned int*)g,
      (__attribute__((address_space(3))) unsigned int*)l, 16, 0, 0);
}

__device__ __forceinline__ void stage64(_Float16* lds, const _Float16* g,
                                        int wid, int lane) {
#pragma unroll
  for (int j = 0; j < 2; ++j) {
    int blk = wid * 2 + j;
    int row = blk * 8 + (lane >> 3);
    int col = (lane & 7) * 8;
    gld_lds16(lds + blk * 512, g + (size_t)row * 1024 + col);
  }
}

__device__ __forceinline__ void stage128(_Float16* lds, const _Float16* g,
                                         int wid, int lane) {
#pragma unroll
  for (int j = 0; j < 4; ++j) {
    int blk = wid * 4 + j;
    int row = blk * 8 + (lane >> 3);
    int col = (lane & 7) * 8;
    gld_lds16(lds + blk * 512, g + (size_t)row * 1024 + col);
  }
}

__device__ __forceinline__ void gemm_core64(const _Float16* __restrict__ A,
                                            const _Float16* __restrict__ W,
                                            _Float16* As, _Float16* Bs,
                                            f32x4 acc[4][2], int m0, int n0, int tid) {
  int lane = tid & 63, wid = tid >> 6;
  int lr = lane & 15, lg = lane >> 4;
  int wn = wid * 32;
  for (int k0 = 0; k0 < 1024; k0 += 64) {
    __syncthreads();
    stage64(As, A + (size_t)m0 * 1024 + k0, wid, lane);
    stage128(Bs, W + (size_t)n0 * 1024 + k0, wid, lane);
    __syncthreads();
#pragma unroll
    for (int ks = 0; ks < 2; ++ks) {
      f16x8 af[4], bfv[2];
#pragma unroll
      for (int mf = 0; mf < 4; ++mf)
        af[mf] = *(const f16x8*)(As + (mf * 16 + lr) * 64 + ks * 32 + lg * 8);
#pragma unroll
      for (int nf = 0; nf < 2; ++nf)
        bfv[nf] = *(const f16x8*)(Bs + (wn + nf * 16 + lr) * 64 + ks * 32 + lg * 8);
#pragma unroll
      for (int mf = 0; mf < 4; ++mf)
#pragma unroll
        for (int nf = 0; nf < 2; ++nf)
          acc[mf][nf] = MFMA32(af[mf], bfv[nf], acc[mf][nf]);
    }
  }
}

// --------------------------------------------------- QKV projection GEMM
#define TRP 72  // Tr stride for 128x64 transpose buffer

__global__ __launch_bounds__(256) void proj_gemm(
    const _Float16* __restrict__ xb,
    const _Float16* __restrict__ wq, const _Float16* __restrict__ wk,
    const _Float16* __restrict__ wv,
    const float* __restrict__ bq, const float* __restrict__ bk,
    const float* __restrict__ bv,
    _Float16* __restrict__ qo, _Float16* __restrict__ ko, _Float16* __restrict__ vo) {
  __shared__ __align__(16) _Float16 smem[12288];   // As 4096 + Bs 8192 halves
  _Float16* As = smem;
  _Float16* Bs = smem + 4096;
  int z = blockIdx.z;
  const _Float16* W = (z == 0) ? wq : ((z == 1) ? wk : wv);
  const float* bias = (z == 0) ? bq : ((z == 1) ? bk : bv);
  int tid = threadIdx.x;
  int m0 = blockIdx.x * 64, n0 = blockIdx.y * 128;
  f32x4 acc[4][2] = {};
  gemm_core64(xb, W, As, Bs, acc, m0, n0, tid);

  int lane = tid & 63, wid = tid >> 6;
  int lr = lane & 15, lg = lane >> 4;
  int wn = wid * 32;

  if (z == 2) {
    _Float16* Tr = smem;                 // reuse As/Bs: 128*72 = 9216 <= 12288
    int b = m0 >> 11, s0 = m0 & 2047;
    __syncthreads();
#pragma unroll
    for (int nf = 0; nf < 2; ++nf) {
      int c = wn + nf * 16 + lr;
      float bb = bias[n0 + c];
#pragma unroll
      for (int mf = 0; mf < 4; ++mf)
#pragma unroll
        for (int i = 0; i < 4; ++i)
          Tr[c * TRP + mf * 16 + lg * 4 + i] = (_Float16)(acc[mf][nf][i] + bb);
    }
    __syncthreads();
#pragma unroll
    for (int j = 0; j < 4; ++j) {
      int cid = tid + 256 * j;
      int c = cid >> 3, seg = cid & 7;
      int cg = n0 + c, h = cg >> 6, hd = cg & 63;
      f16x8 v = *(const f16x8*)(Tr + c * TRP + seg * 8);
      *(f16x8*)(vo + ((size_t)(b * 16 + h) * 64 + hd) * 2048 + s0 + seg * 8) = v;
    }
  } else {
    _Float16* o = (z == 0) ? qo : ko;
#pragma unroll
    for (int nf = 0; nf < 2; ++nf) {
      int col = n0 + wn + nf * 16 + lr;
      float bb = bias[col];
      int h = col >> 6, hd = col & 63;
#pragma unroll
      for (int mf = 0; mf < 4; ++mf)
#pragma unroll
        for (int i = 0; i < 4; ++i) {
          int row = m0 + mf * 16 + lg * 4 + i;
          int b = row >> 11, s = row & 2047;
          o[((size_t)(b * 16 + h) * 2048 + s) * 64 + hd] = (_Float16)(acc[mf][nf][i] + bb);
        }
    }
  }
}

// --------------------------------------------------------- output GEMM (f32)
__global__ __launch_bounds__(256) void out_gemm(
    const _Float16* __restrict__ attn, const _Float16* __restrict__ wo,
    const float* __restrict__ bo, float* __restrict__ out) {
  __shared__ __align__(16) _Float16 smem[12288];
  _Float16* As = smem;
  _Float16* Bs = smem + 4096;
  int tid = threadIdx.x;
  int m0 = blockIdx.x * 64, n0 = blockIdx.y * 128;
  f32x4 acc[4][2] = {};
  gemm_core64(attn, wo, As, Bs, acc, m0, n0, tid);

  int lane = tid & 63, wid = tid >> 6;
  int lr = lane & 15, lg = lane >> 4;
  int wn = wid * 32;
#pragma unroll
  for (int nf = 0; nf < 2; ++nf) {
    int col = n0 + wn + nf * 16 + lr;
    float bb = bo[col];
#pragma unroll
    for (int mf = 0; mf < 4; ++mf)
#pragma unroll
      for (int i = 0; i < 4; ++i) {
        int row = m0 + mf * 16 + lg * 4 + i;
        out[(size_t)row * 1024 + col] = acc[mf][nf][i] + bb;
      }
  }
}

// --------------------------------------------------------- flash attention v14
// r16-exact structure + ONE delta: grid semantics swapped (x = head,
// y = qt-index). Linear id = hh + 16y + 256z -> XCD = hh%8 for ALL y,z:
// each head's K/V (512 KB; 2 MB/XCD <= 4 MB L2) stays L2-resident, so
// prefetch latency drops ~900 -> ~200 cy. Balance unchanged (co-resident
// z=0/z=1 pair still carries qt = y and 15-y).
#define LDP 72  // padded LDS stride (halves)

template <bool MASK>
__device__ __forceinline__ void attn_tile32(const _Float16* Ks, const _Float16* Vs,
                                            const f16x8 qb[2][2], int kv0, int qwb,
                                            int lr, int lg,
                                            float m[2], float l[2], f32x4 ot[2][4]) {
  const float L2E = 1.44269504f;
  const float NINF = -__builtin_inff();
  f16x8 kf0[4], kf1[4];
#pragma unroll
  for (int nf = 0; nf < 4; ++nf) {
    kf0[nf] = *(const f16x8*)(Ks + (nf * 16 + lr) * LDP + lg * 8);
    kf1[nf] = *(const f16x8*)(Ks + (nf * 16 + lr) * LDP + 32 + lg * 8);
  }
  f32x4 sc[2][4];
#pragma unroll
  for (int h = 0; h < 2; ++h)
#pragma unroll
    for (int nf = 0; nf < 4; ++nf) {
      f32x4 z = {0.f, 0.f, 0.f, 0.f};
      z = MFMA32(kf0[nf], qb[h][0], z);
      z = MFMA32(kf1[nf], qb[h][1], z);
      sc[h][nf] = z;
    }
  if (MASK) {
#pragma unroll
    for (int h = 0; h < 2; ++h) {
      int qg = qwb + h * 16 + lr;
#pragma unroll
      for (int nf = 0; nf < 4; ++nf)
#pragma unroll
        for (int i = 0; i < 4; ++i) {
          int kg = kv0 + nf * 16 + lg * 4 + i;
          sc[h][nf][i] = (kg <= qg) ? sc[h][nf][i] : NINF;
        }
    }
  }
  f16x4 pf[2][4];
#pragma unroll
  for (int h = 0; h < 2; ++h) {
    f32x4 mx4 = sc[h][0];
#pragma unroll
    for (int nf = 1; nf < 4; ++nf)
#pragma unroll
      for (int i = 0; i < 4; ++i) mx4[i] = fmaxf(mx4[i], sc[h][nf][i]);
    float tm = fmaxf(fmaxf(mx4[0], mx4[1]), fmaxf(mx4[2], mx4[3]));
    tm = fmaxf(tm, __shfl_xor(tm, 16));
    tm = fmaxf(tm, __shfl_xor(tm, 32));
    float mn = fmaxf(m[h], tm);
    float alpha = __builtin_amdgcn_exp2f((m[h] - mn) * L2E);
    m[h] = mn;
    float mnL = mn * L2E;
    float ps = 0.f;
#pragma unroll
    for (int nf = 0; nf < 4; ++nf)
#pragma unroll
      for (int i = 0; i < 4; ++i) {
        float p = __builtin_amdgcn_exp2f(sc[h][nf][i] * L2E - mnL);
        ps += p;
        pf[h][nf][i] = (_Float16)p;
      }
    ps += __shfl_xor(ps, 16);
    ps += __shfl_xor(ps, 32);
    l[h] = l[h] * alpha + ps;
#pragma unroll
    for (int dt = 0; dt < 4; ++dt)
#pragma unroll
      for (int i = 0; i < 4; ++i) ot[h][dt][i] *= alpha;
  }
#pragma unroll
  for (int nf = 0; nf < 4; ++nf)
#pragma unroll
    for (int dt = 0; dt < 4; ++dt) {
      f16x4 vf = *(const f16x4*)(Vs + (dt * 16 + lr) * LDP + nf * 16 + lg * 4);
      ot[0][dt] = MFMA16(vf, pf[0][nf], ot[0][dt]);
      ot[1][dt] = MFMA16(vf, pf[1][nf], ot[1][dt]);
    }
}

__global__ __launch_bounds__(256) void attn_kernel(
    const _Float16* __restrict__ Q, const _Float16* __restrict__ K,
    const _Float16* __restrict__ VT, _Float16* __restrict__ O) {
  __shared__ __align__(16) _Float16 Ks[2][64 * LDP];
  __shared__ __align__(16) _Float16 Vs[2][64 * LDP];
  int tid = threadIdx.x, lane = tid & 63, wid = tid >> 6;
  int hh = blockIdx.x;                 // head on x -> XCD = hh%8 (K/V L2-local)
  int qt = blockIdx.z ? (15 - (int)blockIdx.y) : (int)blockIdx.y;
  int b = blockIdx.z;
  size_t hoff = (size_t)(b * 16 + hh) * 2048 * 64;
  const _Float16* Qh = Q + hoff;
  const _Float16* Kh = K + hoff;
  const _Float16* VTh = VT + hoff;
  int qwb = qt * 128 + wid * 32;
  int lr = lane & 15, lg = lane >> 4;

  f16x8 qb[2][2];
#pragma unroll
  for (int h = 0; h < 2; ++h) {
    const _Float16* qp = Qh + (size_t)(qwb + h * 16 + lr) * 64;
    qb[h][0] = *(const f16x8*)(qp + lg * 8);
    qb[h][1] = *(const f16x8*)(qp + 32 + lg * 8);
#pragma unroll
    for (int j = 0; j < 8; ++j) {      // fold 1/sqrt(64) into Q (exact: 2^-3)
      qb[h][0][j] *= (_Float16)0.125f;
      qb[h][1][j] *= (_Float16)0.125f;
    }
  }

  float m[2] = {-__builtin_inff(), -__builtin_inff()};
  float l[2] = {0.f, 0.f};
  f32x4 ot[2][4] = {};

  int r0 = tid >> 3, c0 = (tid & 7) * 8;
  int r1 = r0 + 32;
  // prologue: tile 0 -> buf 0
  int4 rk0 = *(const int4*)(Kh + (size_t)r0 * 64 + c0);
  int4 rk1 = *(const int4*)(Kh + (size_t)r1 * 64 + c0);
  int4 rv0 = *(const int4*)(VTh + (size_t)r0 * 2048 + c0);
  int4 rv1 = *(const int4*)(VTh + (size_t)r1 * 2048 + c0);
  *(int4*)(&Ks[0][0] + r0 * LDP + c0) = rk0;
  *(int4*)(&Ks[0][0] + r1 * LDP + c0) = rk1;
  *(int4*)(&Vs[0][0] + r0 * LDP + c0) = rv0;
  *(int4*)(&Vs[0][0] + r1 * LDP + c0) = rv1;
  __syncthreads();

  int aw = qwb >> 6;                   // first masked tile for this wave
  int ntiles = 2 * qt + 2;
  for (int t = 0; t < ntiles; ++t) {
    int cur = t & 1;
    if (t + 1 < ntiles) {              // issue next tile's loads before compute
      int nkv = (t + 1) * 64;
      rk0 = *(const int4*)(Kh + (size_t)(nkv + r0) * 64 + c0);
      rk1 = *(const int4*)(Kh + (size_t)(nkv + r1) * 64 + c0);
      rv0 = *(const int4*)(VTh + (size_t)r0 * 2048 + nkv + c0);
      rv1 = *(const int4*)(VTh + (size_t)r1 * 2048 + nkv + c0);
    }
    if (t < aw)
      attn_tile32<false>(&Ks[cur][0], &Vs[cur][0], qb, t * 64, qwb, lr, lg, m, l, ot);
    else if (t == aw)
      attn_tile32<true>(&Ks[cur][0], &Vs[cur][0], qb, t * 64, qwb, lr, lg, m, l, ot);
    // t > aw: provable no-op (all masked); skip compute, keep barriers
    if (t + 1 < ntiles) {
      *(int4*)(&Ks[cur ^ 1][0] + r0 * LDP + c0) = rk0;
      *(int4*)(&Ks[cur ^ 1][0] + r1 * LDP + c0) = rk1;
      *(int4*)(&Vs[cur ^ 1][0] + r0 * LDP + c0) = rv0;
      *(int4*)(&Vs[cur ^ 1][0] + r1 * LDP + c0) = rv1;
    }
    __syncthreads();
  }

#pragma unroll
  for (int h = 0; h < 2; ++h) {
    float inv = 1.f / l[h];
    _Float16* Oh = O + ((size_t)b * 2048 + qwb + h * 16 + lr) * 1024 + hh * 64;
#pragma unroll
    for (int dt = 0; dt < 4; ++dt) {
      f16x4 o;
#pragma unroll
      for (int i = 0; i < 4; ++i) o[i] = (_Float16)(ot[h][dt][i] * inv);
      *(f16x4*)(Oh + dt * 16 + lg * 4) = o;
    }
  }
}

// ------------------------------------------------------------------- launch
extern "C" void kernel_launch(void* const* d_in, const int* in_sizes, int n_in,
                              void* d_out, int out_size, void* d_ws, size_t ws_size,
                              hipStream_t stream) {
  const float* x  = (const float*)d_in[0];
  const float* Wq = (const float*)d_in[1];
  const float* bq = (const float*)d_in[2];
  const float* Wk = (const float*)d_in[3];
  const float* bk = (const float*)d_in[4];
  const float* Wv = (const float*)d_in[5];
  const float* bv = (const float*)d_in[6];
  const float* Wo = (const float*)d_in[7];
  const float* bo = (const float*)d_in[8];
  float* out = (float*)d_out;

  _Float16* ws  = (_Float16*)d_ws;
  _Float16* xb  = ws;
  _Float16* wqb = ws + 4194304;
  _Float16* wkb = ws + 5242880;
  _Float16* wvb = ws + 6291456;
  _Float16* wob = ws + 7340032;
  _Float16* qw  = ws + 8388608;       // [B,H,S,64]
  _Float16* kw  = ws + 12582912;      // [B,H,S,64]
  _Float16* vtw = ws + 16777216;      // [B,H,64,S]
  _Float16* aw  = ws + 20971520;      // [B,S,1024]

  convert_all<<<8192, 256, 0, stream>>>(x, Wq, Wk, Wv, Wo,
                                        xb, wqb, wkb, wvb, wob);

  proj_gemm<<<dim3(64, 8, 3), 256, 0, stream>>>(xb, wqb, wkb, wvb, bq, bk, bv,
                                                qw, kw, vtw);
  attn_kernel<<<dim3(16, 16, 2), 256, 0, stream>>>(qw, kw, vtw, aw);
  out_gemm<<<dim3(64, 8), 256, 0, stream>>>(aw, wob, bo, out);
}